// Round 5
// baseline (245.932 us; speedup 1.0000x reference)
//
#include <hip/hip_runtime.h>
#include <hip/hip_bf16.h>

#define FIN 256
#define HID 128
#define BSH 7            // bucket = dst >> 7 (128 nodes/bucket)
#define NBK_MAX 1024
#define EPB 4096         // edges per block in hist/pair kernels

typedef __attribute__((ext_vector_type(8))) short short8v;   // bf16x8 MFMA frag
typedef __attribute__((ext_vector_type(4))) float f32x4;     // MFMA acc

static __device__ __forceinline__ unsigned short f2bf(float f) {
    unsigned int u = __float_as_uint(f);
    u += 0x7fffu + ((u >> 16) & 1u);   // RNE
    return (unsigned short)(u >> 16);
}
static __device__ __forceinline__ void split_bf16(float f, unsigned short& hi, unsigned short& lo) {
    unsigned int u = __float_as_uint(f);
    unsigned int uh = (u + (0x7fffu + ((u >> 16) & 1u))) & 0xffff0000u;
    hi = (unsigned short)(uh >> 16);
    float fl = f - __uint_as_float(uh);
    unsigned int ul = __float_as_uint(fl);
    lo = (unsigned short)((ul + (0x7fffu + ((ul >> 16) & 1u))) >> 16);
}

// ---------------- bucket histogram via LDS ----------------
__global__ __launch_bounds__(256) void k_hist(const int* __restrict__ dst, int* __restrict__ bcnt,
                                              int nbk, int e) {
    __shared__ int cnt[NBK_MAX];
    int t = threadIdx.x;
    for (int b = t; b < nbk; b += 256) cnt[b] = 0;
    __syncthreads();
    int e0 = blockIdx.x * EPB;
    #pragma unroll
    for (int j = 0; j < EPB; j += 256) {
        int idx = e0 + j + t;
        if (idx < e) atomicAdd(&cnt[dst[idx] >> BSH], 1);
    }
    __syncthreads();
    for (int b = t; b < nbk; b += 256)
        if (cnt[b]) atomicAdd(&bcnt[b], cnt[b]);
}

// ---------------- bucket scan (single block) ----------------
__global__ __launch_bounds__(1024) void k_bscan(const int* __restrict__ bcnt, int* __restrict__ bo,
                                                int* __restrict__ bcur, int nbk, int e) {
    __shared__ int sm[1024];
    int t = threadIdx.x;
    int v = (t < nbk) ? bcnt[t] : 0;
    sm[t] = v;
    __syncthreads();
    int acc = v;
    for (int off = 1; off < 1024; off <<= 1) {
        int u = (t >= off) ? sm[t - off] : 0;
        __syncthreads();
        acc += u;
        sm[t] = acc;
        __syncthreads();
    }
    if (t < nbk) { bo[t] = acc - v; bcur[t] = acc - v; }
    if (t == 0) bo[nbk] = e;
}

// ---------------- two-phase pair scatter (LDS counts, 1 global atomic per block-bucket) ----------------
__global__ __launch_bounds__(256) void k_pair2(const int* __restrict__ src, const int* __restrict__ dst,
                                               int* __restrict__ bcur, int2* __restrict__ pairs,
                                               int nbk, int e) {
    __shared__ int cnt[NBK_MAX];
    __shared__ int base[NBK_MAX];
    const int t = threadIdx.x;
    for (int b = t; b < nbk; b += 256) cnt[b] = 0;
    __syncthreads();
    const int e0 = blockIdx.x * EPB;
    int s[16], d[16], lo[16];
    #pragma unroll
    for (int j = 0; j < 16; ++j) {
        int idx = e0 + j * 256 + t;
        if (idx < e) {
            s[j] = src[idx];
            d[j] = dst[idx];
            lo[j] = atomicAdd(&cnt[d[j] >> BSH], 1);
        }
    }
    __syncthreads();
    for (int b = t; b < nbk; b += 256)
        base[b] = cnt[b] ? atomicAdd(&bcur[b], cnt[b]) : 0;
    __syncthreads();
    #pragma unroll
    for (int j = 0; j < 16; ++j) {
        int idx = e0 + j * 256 + t;
        if (idx < e) pairs[base[d[j] >> BSH] + lo[j]] = make_int2(s[j], d[j]);
    }
}

// ---------------- per-bucket degree (LDS histogram, plain stores) ----------------
__global__ __launch_bounds__(256) void k_bdeg(const int2* __restrict__ pairs, const int* __restrict__ bo,
                                              int* __restrict__ deg, int n) {
    __shared__ int cnt[128];
    const int b = blockIdx.x, t = threadIdx.x;
    if (t < 128) cnt[t] = 0;
    __syncthreads();
    int beg = bo[b], end = bo[b + 1];
    for (int i = beg + t; i < end; i += 256) atomicAdd(&cnt[pairs[i].y & 127], 1);
    __syncthreads();
    int node = (b << BSH) + t;
    if (t < 128 && node < n) deg[node] = cnt[t];
}

// ---------------- 3-kernel exclusive scan over deg ----------------
__global__ __launch_bounds__(256) void k_scan1(const int* __restrict__ deg, int* __restrict__ partial,
                                               int* __restrict__ bsum, int n) {
    __shared__ int sm[256];
    int t = threadIdx.x;
    int i = blockIdx.x * 256 + t;
    int v = (i < n) ? deg[i] : 0;
    sm[t] = v;
    __syncthreads();
    int acc = v;
    for (int off = 1; off < 256; off <<= 1) {
        int u = (t >= off) ? sm[t - off] : 0;
        __syncthreads();
        acc += u;
        sm[t] = acc;
        __syncthreads();
    }
    if (i < n) partial[i] = acc;
    if (t == 255) bsum[blockIdx.x] = acc;
}

__global__ __launch_bounds__(512) void k_scan2(const int* __restrict__ bsum, int* __restrict__ boff, int nb) {
    __shared__ int sm[512];
    int t = threadIdx.x;
    int v = (t < nb) ? bsum[t] : 0;
    sm[t] = v;
    __syncthreads();
    int acc = v;
    for (int off = 1; off < 512; off <<= 1) {
        int u = (t >= off) ? sm[t - off] : 0;
        __syncthreads();
        acc += u;
        sm[t] = acc;
        __syncthreads();
    }
    if (t < nb) boff[t] = acc - v;
}

__global__ __launch_bounds__(256) void k_scan3(const int* __restrict__ deg, const int* __restrict__ partial,
                                               const int* __restrict__ boff, int* __restrict__ rowptr,
                                               float* __restrict__ dinv, int n, int e) {
    int i = blockIdx.x * 256 + threadIdx.x;
    if (i >= n) return;
    rowptr[i] = boff[blockIdx.x] + partial[i] - deg[i];
    dinv[i] = rsqrtf((float)(deg[i] + 1));
    if (i == 0) rowptr[n] = e;
}

// ---------------- per-bucket CSR fill (LDS cursors seeded from rowptr) ----------------
__global__ __launch_bounds__(256) void k_bfill(const int2* __restrict__ pairs, const int* __restrict__ bo,
                                               const int* __restrict__ rowptr, int* __restrict__ csr_src,
                                               int n) {
    __shared__ int cur[128];
    const int b = blockIdx.x, t = threadIdx.x;
    int node = (b << BSH) + t;
    if (t < 128) cur[t] = (node < n) ? rowptr[node] : 0;
    __syncthreads();
    int beg = bo[b], end = bo[b + 1];
    for (int i = beg + t; i < end; i += 256) {
        int2 pr = pairs[i];
        int p = atomicAdd(&cur[pr.y & 127], 1);
        csr_src[p] = pr.x;
    }
}

// ---------------- W1 pre-split (once) ----------------
__global__ void k_wsplit(const float* __restrict__ W1, unsigned short* __restrict__ Whi,
                         unsigned short* __restrict__ Wlo, int total) {
    int i = blockIdx.x * 256 + threadIdx.x;
    if (i < total) {
        unsigned short h, l;
        split_bf16(W1[i], h, l);
        Whi[i] = h; Wlo[i] = l;
    }
}

// ---------------- GEMM1: LDS-free, barrier-free split-bf16 3-pass MFMA ----------------
// Block = 128 M-rows, 4 waves; wave owns 32 rows x all 128 N.
// A frags: straight from global x (fp32), split in regs. B frags: straight from
// L2-resident Whi/Wlo (lane l reads 16B of W row (nt*16 + (l&15)) at k-offset (l>>4)*8).
__global__ __launch_bounds__(256) void k_gemm(const float* __restrict__ x,
                                              const unsigned short* __restrict__ Whi,
                                              const unsigned short* __restrict__ Wlo,
                                              const float* __restrict__ dinv,
                                              unsigned short* __restrict__ hs, int n) {
    const int tid = threadIdx.x;
    const int l   = tid & 63;
    const int w   = tid >> 6;
    const int fr  = l & 15;
    const int kg  = l >> 4;
    const int i0  = blockIdx.x * 128 + w * 32;

    const int r0 = i0 + fr;
    const int r1 = i0 + 16 + fr;
    // clamp OOB rows to row 0 (results discarded by guarded store)
    const float* xp0 = &x[(size_t)(r0 < n ? r0 : 0) * FIN + kg * 8];
    const float* xp1 = &x[(size_t)(r1 < n ? r1 : 0) * FIN + kg * 8];
    const unsigned short* wb = &Whi[fr * FIN + kg * 8];
    const unsigned short* wl = &Wlo[fr * FIN + kg * 8];

    f32x4 acc[2][8] = {};

    for (int kb = 0; kb < FIN; kb += 32) {
        float a0[8], a1[8];
        *(float4*)&a0[0] = *(const float4*)&xp0[kb];
        *(float4*)&a0[4] = *(const float4*)&xp0[kb + 4];
        *(float4*)&a1[0] = *(const float4*)&xp1[kb];
        *(float4*)&a1[4] = *(const float4*)&xp1[kb + 4];
        short8v ah0, al0, ah1, al1;
        #pragma unroll
        for (int j = 0; j < 8; ++j) {
            unsigned short h, lo_;
            split_bf16(a0[j], h, lo_); ah0[j] = (short)h; al0[j] = (short)lo_;
            split_bf16(a1[j], h, lo_); ah1[j] = (short)h; al1[j] = (short)lo_;
        }
        #pragma unroll
        for (int nt = 0; nt < 8; ++nt) {
            const int off = nt * 16 * FIN + kb;
            short8v bh = *(const short8v*)&wb[off];
            short8v bl = *(const short8v*)&wl[off];
            acc[0][nt] = __builtin_amdgcn_mfma_f32_16x16x32_bf16(al0, bh, acc[0][nt], 0, 0, 0);
            acc[0][nt] = __builtin_amdgcn_mfma_f32_16x16x32_bf16(ah0, bl, acc[0][nt], 0, 0, 0);
            acc[0][nt] = __builtin_amdgcn_mfma_f32_16x16x32_bf16(ah0, bh, acc[0][nt], 0, 0, 0);
            acc[1][nt] = __builtin_amdgcn_mfma_f32_16x16x32_bf16(al1, bh, acc[1][nt], 0, 0, 0);
            acc[1][nt] = __builtin_amdgcn_mfma_f32_16x16x32_bf16(ah1, bl, acc[1][nt], 0, 0, 0);
            acc[1][nt] = __builtin_amdgcn_mfma_f32_16x16x32_bf16(ah1, bh, acc[1][nt], 0, 0, 0);
        }
    }

    // D(m,n): row = kg*4 + reg (M), col = fr (N)  [same verified mapping as r3/r4]
    #pragma unroll
    for (int mt = 0; mt < 2; ++mt) {
        int rbase = i0 + mt * 16 + kg * 4;
        if (rbase < n) {
            float4 dv = *(const float4*)&dinv[rbase];
            #pragma unroll
            for (int nt = 0; nt < 8; ++nt) {
                f32x4 c = acc[mt][nt];
                int col = nt * 16 + fr;
                #pragma unroll
                for (int r = 0; r < 4; ++r) {
                    int gi = rbase + r;
                    if (gi < n)
                        hs[(size_t)gi * HID + col] = f2bf(((const float*)&c)[r] * ((const float*)&dv)[r]);
                }
            }
        }
    }
}

// ---------------- layer-1 aggregation fused with layer-2 dot ----------------
__global__ __launch_bounds__(256) void k_agg1(const unsigned int* __restrict__ hs,
                                              const int* __restrict__ rowptr,
                                              const int* __restrict__ csr_src,
                                              const float* __restrict__ dinv,
                                              const float* __restrict__ b1, const float* __restrict__ W2,
                                              float* __restrict__ zs, int n) {
    int i = (blockIdx.x << 2) + (threadIdx.x >> 6);
    if (i >= n) return;
    const int lane = threadIdx.x & 63;

    unsigned int sv = hs[(i << 6) + lane];                 // self-loop term
    float ax = __uint_as_float(sv << 16);
    float ay = __uint_as_float(sv & 0xffff0000u);

    int e = rowptr[i];
    const int end = rowptr[i + 1];
    while (e < end) {
        int cnt = end - e;
        if (cnt > 64) cnt = 64;
        int sidx = (lane < cnt) ? csr_src[e + lane] : 0;
        int j = 0;
        for (; j + 2 <= cnt; j += 2) {
            int s0 = __shfl(sidx, j, 64);
            int s1 = __shfl(sidx, j + 1, 64);
            unsigned int v0 = hs[(s0 << 6) + lane];
            unsigned int v1 = hs[(s1 << 6) + lane];
            ax += __uint_as_float(v0 << 16);
            ay += __uint_as_float(v0 & 0xffff0000u);
            ax += __uint_as_float(v1 << 16);
            ay += __uint_as_float(v1 & 0xffff0000u);
        }
        if (j < cnt) {
            int s0 = __shfl(sidx, j, 64);
            unsigned int v0 = hs[(s0 << 6) + lane];
            ax += __uint_as_float(v0 << 16);
            ay += __uint_as_float(v0 & 0xffff0000u);
        }
        e += cnt;
    }
    float di = dinv[i];
    float2 bb = ((const float2*)b1)[lane];
    float h0 = fmaxf(ax * di + bb.x, 0.f);
    float h1 = fmaxf(ay * di + bb.y, 0.f);
    float2 w2 = ((const float2*)W2)[lane];
    float z = h0 * w2.x + h1 * w2.y;
    #pragma unroll
    for (int off = 32; off; off >>= 1) z += __shfl_xor(z, off, 64);
    if (lane == 0) zs[i] = z * di;
}

// ---------------- layer-2 aggregation ----------------
__global__ void k_agg2(const float* __restrict__ zs, const int* __restrict__ rowptr,
                       const int* __restrict__ csr_src, const float* __restrict__ dinv,
                       const float* __restrict__ b2, float* __restrict__ out, int n) {
    int i = blockIdx.x * blockDim.x + threadIdx.x;
    if (i >= n) return;
    float acc = zs[i];
    int beg = rowptr[i], end = rowptr[i + 1];
    for (int e = beg; e < end; ++e) acc += zs[csr_src[e]];
    out[i] = acc * dinv[i] + b2[0];
}

extern "C" void kernel_launch(void* const* d_in, const int* in_sizes, int n_in,
                              void* d_out, int out_size, void* d_ws, size_t ws_size,
                              hipStream_t stream) {
    const float* x  = (const float*)d_in[0];
    const int*   ei = (const int*)d_in[1];
    const float* W1 = (const float*)d_in[2];
    const float* b1 = (const float*)d_in[3];
    const float* W2 = (const float*)d_in[4];
    const float* b2 = (const float*)d_in[5];
    float* out = (float*)d_out;

    const int n = in_sizes[0] / FIN;
    const int e = in_sizes[1] / 2;
    const int* src = ei;
    const int* dst = ei + e;
    const int nbk = (n + (1 << BSH) - 1) >> BSH;

    char* p = (char*)d_ws;
    auto carve = [&](size_t bytes) { char* q = p; p += (bytes + 255) & ~(size_t)255; return q; };
    int*            deg     = (int*)carve((size_t)n * 4);
    int*            bcnt    = (int*)carve((size_t)NBK_MAX * 4);
    int*            partial = (int*)carve((size_t)n * 4);
    int*            bsum    = (int*)carve(4096);
    int*            boff    = (int*)carve(4096);
    int*            bo      = (int*)carve((size_t)(NBK_MAX + 1) * 4);
    int*            bcur    = (int*)carve((size_t)NBK_MAX * 4);
    int*            rowptr  = (int*)carve((size_t)(n + 1) * 4);
    float*          dinv    = (float*)carve((size_t)n * 4);
    int*            csr     = (int*)carve((size_t)e * 4);
    int2*           pairs   = (int2*)carve((size_t)e * 8);
    unsigned short* hs      = (unsigned short*)carve((size_t)n * HID * 2);
    float*          zs      = (float*)carve((size_t)n * 4);
    unsigned short* Whi     = (unsigned short*)carve((size_t)HID * FIN * 2);
    unsigned short* Wlo     = (unsigned short*)carve((size_t)HID * FIN * 2);

    hipMemsetAsync(bcnt, 0, (size_t)NBK_MAX * 4, stream);

    const int nb  = (n + 255) / 256;
    const int neb = (e + EPB - 1) / EPB;
    k_wsplit<<<(HID * FIN + 255) / 256, 256, 0, stream>>>(W1, Whi, Wlo, HID * FIN);
    k_hist <<<neb, 256, 0, stream>>>(dst, bcnt, nbk, e);
    k_bscan<<<1, 1024, 0, stream>>>(bcnt, bo, bcur, nbk, e);
    k_pair2<<<neb, 256, 0, stream>>>(src, dst, bcur, pairs, nbk, e);
    k_bdeg <<<nbk, 256, 0, stream>>>(pairs, bo, deg, n);
    k_scan1<<<nb, 256, 0, stream>>>(deg, partial, bsum, n);
    k_scan2<<<1, 512, 0, stream>>>(bsum, boff, nb);
    k_scan3<<<nb, 256, 0, stream>>>(deg, partial, boff, rowptr, dinv, n, e);
    k_bfill<<<nbk, 256, 0, stream>>>(pairs, bo, rowptr, csr, n);
    k_gemm <<<(n + 127) / 128, 256, 0, stream>>>(x, Whi, Wlo, dinv, hs, n);
    k_agg1 <<<(n + 3) / 4, 256, 0, stream>>>((const unsigned int*)hs, rowptr, csr, dinv, b1, W2, zs, n);
    k_agg2 <<<(n + 255) / 256, 256, 0, stream>>>(zs, rowptr, csr, dinv, b2, out, n);
}

// Round 6
// 228.245 us; speedup vs baseline: 1.0775x; 1.0775x over previous
//
#include <hip/hip_runtime.h>
#include <hip/hip_bf16.h>
#include <hip/hip_fp16.h>

#define FIN 256
#define HID 128
#define BSH 7            // bucket = dst >> 7 (128 nodes/bucket)
#define NBK_MAX 1024
#define EPB 4096         // edges per block in hist/pair kernels

typedef __attribute__((ext_vector_type(8))) _Float16 half8v;  // f16x8 MFMA frag (4 VGPRs)
typedef __attribute__((ext_vector_type(4))) float f32x4;      // MFMA acc

// ---------------- bucket histogram via LDS ----------------
__global__ __launch_bounds__(256) void k_hist(const int* __restrict__ dst, int* __restrict__ bcnt,
                                              int nbk, int e) {
    __shared__ int cnt[NBK_MAX];
    int t = threadIdx.x;
    for (int b = t; b < nbk; b += 256) cnt[b] = 0;
    __syncthreads();
    int e0 = blockIdx.x * EPB;
    #pragma unroll
    for (int j = 0; j < EPB; j += 256) {
        int idx = e0 + j + t;
        if (idx < e) atomicAdd(&cnt[dst[idx] >> BSH], 1);
    }
    __syncthreads();
    for (int b = t; b < nbk; b += 256)
        if (cnt[b]) atomicAdd(&bcnt[b], cnt[b]);
}

// ---------------- bucket scan (single block) ----------------
__global__ __launch_bounds__(1024) void k_bscan(const int* __restrict__ bcnt, int* __restrict__ bo,
                                                int* __restrict__ bcur, int nbk, int e) {
    __shared__ int sm[1024];
    int t = threadIdx.x;
    int v = (t < nbk) ? bcnt[t] : 0;
    sm[t] = v;
    __syncthreads();
    int acc = v;
    for (int off = 1; off < 1024; off <<= 1) {
        int u = (t >= off) ? sm[t - off] : 0;
        __syncthreads();
        acc += u;
        sm[t] = acc;
        __syncthreads();
    }
    if (t < nbk) { bo[t] = acc - v; bcur[t] = acc - v; }
    if (t == 0) bo[nbk] = e;
}

// ---------------- two-phase pair scatter (LDS counts, 1 global atomic per block-bucket) ----------------
__global__ __launch_bounds__(256) void k_pair2(const int* __restrict__ src, const int* __restrict__ dst,
                                               int* __restrict__ bcur, int2* __restrict__ pairs,
                                               int nbk, int e) {
    __shared__ int cnt[NBK_MAX];
    __shared__ int base[NBK_MAX];
    const int t = threadIdx.x;
    for (int b = t; b < nbk; b += 256) cnt[b] = 0;
    __syncthreads();
    const int e0 = blockIdx.x * EPB;
    int s[16], d[16], lo[16];
    #pragma unroll
    for (int j = 0; j < 16; ++j) {
        int idx = e0 + j * 256 + t;
        if (idx < e) {
            s[j] = src[idx];
            d[j] = dst[idx];
            lo[j] = atomicAdd(&cnt[d[j] >> BSH], 1);
        }
    }
    __syncthreads();
    for (int b = t; b < nbk; b += 256)
        base[b] = cnt[b] ? atomicAdd(&bcur[b], cnt[b]) : 0;
    __syncthreads();
    #pragma unroll
    for (int j = 0; j < 16; ++j) {
        int idx = e0 + j * 256 + t;
        if (idx < e) pairs[base[d[j] >> BSH] + lo[j]] = make_int2(s[j], d[j]);
    }
}

// ---------------- per-bucket degree (LDS histogram, plain stores) ----------------
__global__ __launch_bounds__(256) void k_bdeg(const int2* __restrict__ pairs, const int* __restrict__ bo,
                                              int* __restrict__ deg, int n) {
    __shared__ int cnt[128];
    const int b = blockIdx.x, t = threadIdx.x;
    if (t < 128) cnt[t] = 0;
    __syncthreads();
    int beg = bo[b], end = bo[b + 1];
    for (int i = beg + t; i < end; i += 256) atomicAdd(&cnt[pairs[i].y & 127], 1);
    __syncthreads();
    int node = (b << BSH) + t;
    if (t < 128 && node < n) deg[node] = cnt[t];
}

// ---------------- 3-kernel exclusive scan over deg ----------------
__global__ __launch_bounds__(256) void k_scan1(const int* __restrict__ deg, int* __restrict__ partial,
                                               int* __restrict__ bsum, int n) {
    __shared__ int sm[256];
    int t = threadIdx.x;
    int i = blockIdx.x * 256 + t;
    int v = (i < n) ? deg[i] : 0;
    sm[t] = v;
    __syncthreads();
    int acc = v;
    for (int off = 1; off < 256; off <<= 1) {
        int u = (t >= off) ? sm[t - off] : 0;
        __syncthreads();
        acc += u;
        sm[t] = acc;
        __syncthreads();
    }
    if (i < n) partial[i] = acc;
    if (t == 255) bsum[blockIdx.x] = acc;
}

__global__ __launch_bounds__(512) void k_scan2(const int* __restrict__ bsum, int* __restrict__ boff, int nb) {
    __shared__ int sm[512];
    int t = threadIdx.x;
    int v = (t < nb) ? bsum[t] : 0;
    sm[t] = v;
    __syncthreads();
    int acc = v;
    for (int off = 1; off < 512; off <<= 1) {
        int u = (t >= off) ? sm[t - off] : 0;
        __syncthreads();
        acc += u;
        sm[t] = acc;
        __syncthreads();
    }
    if (t < nb) boff[t] = acc - v;
}

__global__ __launch_bounds__(256) void k_scan3(const int* __restrict__ deg, const int* __restrict__ partial,
                                               const int* __restrict__ boff, int* __restrict__ rowptr,
                                               float* __restrict__ dinv, int n, int e) {
    int i = blockIdx.x * 256 + threadIdx.x;
    if (i >= n) return;
    rowptr[i] = boff[blockIdx.x] + partial[i] - deg[i];
    dinv[i] = rsqrtf((float)(deg[i] + 1));
    if (i == 0) rowptr[n] = e;
}

// ---------------- per-bucket CSR fill (LDS cursors seeded from rowptr) ----------------
__global__ __launch_bounds__(256) void k_bfill(const int2* __restrict__ pairs, const int* __restrict__ bo,
                                               const int* __restrict__ rowptr, int* __restrict__ csr_src,
                                               int n) {
    __shared__ int cur[128];
    const int b = blockIdx.x, t = threadIdx.x;
    int node = (b << BSH) + t;
    if (t < 128) cur[t] = (node < n) ? rowptr[node] : 0;
    __syncthreads();
    int beg = bo[b], end = bo[b + 1];
    for (int i = beg + t; i < end; i += 256) {
        int2 pr = pairs[i];
        int p = atomicAdd(&cur[pr.y & 127], 1);
        csr_src[p] = pr.x;
    }
}

// ---------------- W1 -> fp16 (once) ----------------
__global__ void k_whalf(const float* __restrict__ W1, _Float16* __restrict__ Wh, int total) {
    int i = blockIdx.x * 256 + threadIdx.x;
    if (i < total) Wh[i] = (_Float16)W1[i];
}

// ---------------- GEMM1: LDS-free single-pass fp16 MFMA ----------------
// Block = 64 M-rows, 4 waves; wave owns 16 rows x all 128 N (8 nt frags, 32 AGPR acc).
// A frags from global x (fp32->fp16 in regs, next-K prefetch); B frags from L2-resident Wh.
__global__ __launch_bounds__(256) void k_gemm(const float* __restrict__ x,
                                              const _Float16* __restrict__ Wh,
                                              const float* __restrict__ dinv,
                                              __half* __restrict__ hs, int n) {
    const int tid = threadIdx.x;
    const int l   = tid & 63;
    const int w   = tid >> 6;
    const int fr  = l & 15;
    const int kg  = l >> 4;
    const int i0  = blockIdx.x * 64 + w * 16;

    const int r0 = i0 + fr;
    const float* xp = &x[(size_t)(r0 < n ? r0 : 0) * FIN + kg * 8];
    const _Float16* wp = &Wh[fr * FIN + kg * 8];

    f32x4 acc[8] = {};

    float4 c0 = *(const float4*)&xp[0];
    float4 c1 = *(const float4*)&xp[4];
    #pragma unroll
    for (int ks = 0; ks < 8; ++ks) {
        float4 a0 = c0, a1 = c1;
        if (ks < 7) {
            c0 = *(const float4*)&xp[(ks + 1) * 32];
            c1 = *(const float4*)&xp[(ks + 1) * 32 + 4];
        }
        half8v ha;
        ha[0] = (_Float16)a0.x; ha[1] = (_Float16)a0.y;
        ha[2] = (_Float16)a0.z; ha[3] = (_Float16)a0.w;
        ha[4] = (_Float16)a1.x; ha[5] = (_Float16)a1.y;
        ha[6] = (_Float16)a1.z; ha[7] = (_Float16)a1.w;
        #pragma unroll
        for (int nt = 0; nt < 8; ++nt) {
            half8v hb = *(const half8v*)&wp[nt * 16 * FIN + ks * 32];
            acc[nt] = __builtin_amdgcn_mfma_f32_16x16x32_f16(ha, hb, acc[nt], 0, 0, 0);
        }
    }

    // D(m,n): row = kg*4 + reg (M), col = fr (N)
    int rbase = i0 + kg * 4;
    if (rbase < n) {
        float4 dv = *(const float4*)&dinv[rbase];
        #pragma unroll
        for (int nt = 0; nt < 8; ++nt) {
            f32x4 c = acc[nt];
            int col = nt * 16 + fr;
            #pragma unroll
            for (int r = 0; r < 4; ++r) {
                int gi = rbase + r;
                if (gi < n)
                    hs[(size_t)gi * HID + col] = __float2half(((const float*)&c)[r] * ((const float*)&dv)[r]);
            }
        }
    }
}

// ---------------- layer-1 aggregation fused with layer-2 dot ----------------
// one wave per node; hs rows are fp16 (lane owns features 2*lane, 2*lane+1)
__global__ __launch_bounds__(256) void k_agg1(const unsigned int* __restrict__ hs,
                                              const int* __restrict__ rowptr,
                                              const int* __restrict__ csr_src,
                                              const float* __restrict__ dinv,
                                              const float* __restrict__ b1, const float* __restrict__ W2,
                                              float* __restrict__ zs, int n) {
    int i = (blockIdx.x << 2) + (threadIdx.x >> 6);
    if (i >= n) return;
    const int lane = threadIdx.x & 63;

    unsigned int sv = hs[(i << 6) + lane];                 // self-loop term
    float2 a = __half22float2(*reinterpret_cast<__half2*>(&sv));
    float ax = a.x, ay = a.y;

    int e = rowptr[i];
    const int end = rowptr[i + 1];
    while (e < end) {
        int cnt = end - e;
        if (cnt > 64) cnt = 64;
        int sidx = (lane < cnt) ? csr_src[e + lane] : 0;
        int j = 0;
        for (; j + 2 <= cnt; j += 2) {
            int s0 = __shfl(sidx, j, 64);
            int s1 = __shfl(sidx, j + 1, 64);
            unsigned int v0 = hs[(s0 << 6) + lane];
            unsigned int v1 = hs[(s1 << 6) + lane];
            float2 f0 = __half22float2(*reinterpret_cast<__half2*>(&v0));
            float2 f1 = __half22float2(*reinterpret_cast<__half2*>(&v1));
            ax += f0.x; ay += f0.y;
            ax += f1.x; ay += f1.y;
        }
        if (j < cnt) {
            int s0 = __shfl(sidx, j, 64);
            unsigned int v0 = hs[(s0 << 6) + lane];
            float2 f0 = __half22float2(*reinterpret_cast<__half2*>(&v0));
            ax += f0.x; ay += f0.y;
        }
        e += cnt;
    }
    float di = dinv[i];
    float2 bb = ((const float2*)b1)[lane];
    float h0 = fmaxf(ax * di + bb.x, 0.f);
    float h1 = fmaxf(ay * di + bb.y, 0.f);
    float2 w2 = ((const float2*)W2)[lane];
    float z = h0 * w2.x + h1 * w2.y;
    #pragma unroll
    for (int off = 32; off; off >>= 1) z += __shfl_xor(z, off, 64);
    if (lane == 0) zs[i] = z * di;
}

// ---------------- layer-2 aggregation ----------------
__global__ void k_agg2(const float* __restrict__ zs, const int* __restrict__ rowptr,
                       const int* __restrict__ csr_src, const float* __restrict__ dinv,
                       const float* __restrict__ b2, float* __restrict__ out, int n) {
    int i = blockIdx.x * blockDim.x + threadIdx.x;
    if (i >= n) return;
    float acc = zs[i];
    int beg = rowptr[i], end = rowptr[i + 1];
    for (int e = beg; e < end; ++e) acc += zs[csr_src[e]];
    out[i] = acc * dinv[i] + b2[0];
}

extern "C" void kernel_launch(void* const* d_in, const int* in_sizes, int n_in,
                              void* d_out, int out_size, void* d_ws, size_t ws_size,
                              hipStream_t stream) {
    const float* x  = (const float*)d_in[0];
    const int*   ei = (const int*)d_in[1];
    const float* W1 = (const float*)d_in[2];
    const float* b1 = (const float*)d_in[3];
    const float* W2 = (const float*)d_in[4];
    const float* b2 = (const float*)d_in[5];
    float* out = (float*)d_out;

    const int n = in_sizes[0] / FIN;
    const int e = in_sizes[1] / 2;
    const int* src = ei;
    const int* dst = ei + e;
    const int nbk = (n + (1 << BSH) - 1) >> BSH;

    char* p = (char*)d_ws;
    auto carve = [&](size_t bytes) { char* q = p; p += (bytes + 255) & ~(size_t)255; return q; };
    int*            deg     = (int*)carve((size_t)n * 4);
    int*            bcnt    = (int*)carve((size_t)NBK_MAX * 4);
    int*            partial = (int*)carve((size_t)n * 4);
    int*            bsum    = (int*)carve(4096);
    int*            boff    = (int*)carve(4096);
    int*            bo      = (int*)carve((size_t)(NBK_MAX + 1) * 4);
    int*            bcur    = (int*)carve((size_t)NBK_MAX * 4);
    int*            rowptr  = (int*)carve((size_t)(n + 1) * 4);
    float*          dinv    = (float*)carve((size_t)n * 4);
    int*            csr     = (int*)carve((size_t)e * 4);
    int2*           pairs   = (int2*)carve((size_t)e * 8);
    __half*         hs      = (__half*)carve((size_t)n * HID * 2);
    float*          zs      = (float*)carve((size_t)n * 4);
    _Float16*       Wh      = (_Float16*)carve((size_t)HID * FIN * 2);

    hipMemsetAsync(bcnt, 0, (size_t)NBK_MAX * 4, stream);

    const int nb  = (n + 255) / 256;
    const int neb = (e + EPB - 1) / EPB;
    k_whalf<<<(HID * FIN + 255) / 256, 256, 0, stream>>>(W1, Wh, HID * FIN);
    k_hist <<<neb, 256, 0, stream>>>(dst, bcnt, nbk, e);
    k_bscan<<<1, 1024, 0, stream>>>(bcnt, bo, bcur, nbk, e);
    k_pair2<<<neb, 256, 0, stream>>>(src, dst, bcur, pairs, nbk, e);
    k_bdeg <<<nbk, 256, 0, stream>>>(pairs, bo, deg, n);
    k_scan1<<<nb, 256, 0, stream>>>(deg, partial, bsum, n);
    k_scan2<<<1, 512, 0, stream>>>(bsum, boff, nb);
    k_scan3<<<nb, 256, 0, stream>>>(deg, partial, boff, rowptr, dinv, n, e);
    k_bfill<<<nbk, 256, 0, stream>>>(pairs, bo, rowptr, csr, n);
    k_gemm <<<(n + 63) / 64, 256, 0, stream>>>(x, Wh, dinv, hs, n);
    k_agg1 <<<(n + 3) / 4, 256, 0, stream>>>((const unsigned int*)hs, rowptr, csr, dinv, b1, W2, zs, n);
    k_agg2 <<<(n + 255) / 256, 256, 0, stream>>>(zs, rowptr, csr, dinv, b2, out, n);
}

// Round 7
// 188.365 us; speedup vs baseline: 1.3056x; 1.2117x over previous
//
#include <hip/hip_runtime.h>
#include <hip/hip_bf16.h>
#include <hip/hip_fp16.h>

#define FIN 256
#define HID 128
#define BSH 7            // bucket = dst >> 7 (128 nodes/bucket)
#define NBK_MAX 1024
#define EPB 4096         // edges per block in hist/pair kernels
#define WPAD 264         // 256 + 8 halfs row pad

typedef __attribute__((ext_vector_type(8))) _Float16 half8v;  // f16x8 MFMA frag (4 VGPRs)
typedef __attribute__((ext_vector_type(4))) float f32x4;      // MFMA acc

// ---------------- bucket histogram via LDS ----------------
__global__ __launch_bounds__(256) void k_hist(const int* __restrict__ dst, int* __restrict__ bcnt,
                                              int nbk, int e) {
    __shared__ int cnt[NBK_MAX];
    int t = threadIdx.x;
    for (int b = t; b < nbk; b += 256) cnt[b] = 0;
    __syncthreads();
    int e0 = blockIdx.x * EPB;
    #pragma unroll
    for (int j = 0; j < EPB; j += 256) {
        int idx = e0 + j + t;
        if (idx < e) atomicAdd(&cnt[dst[idx] >> BSH], 1);
    }
    __syncthreads();
    for (int b = t; b < nbk; b += 256)
        if (cnt[b]) atomicAdd(&bcnt[b], cnt[b]);
}

// ---------------- bucket scan (single block) ----------------
__global__ __launch_bounds__(1024) void k_bscan(const int* __restrict__ bcnt, int* __restrict__ bo,
                                                int* __restrict__ bcur, int nbk, int e) {
    __shared__ int sm[1024];
    int t = threadIdx.x;
    int v = (t < nbk) ? bcnt[t] : 0;
    sm[t] = v;
    __syncthreads();
    int acc = v;
    for (int off = 1; off < 1024; off <<= 1) {
        int u = (t >= off) ? sm[t - off] : 0;
        __syncthreads();
        acc += u;
        sm[t] = acc;
        __syncthreads();
    }
    if (t < nbk) { bo[t] = acc - v; bcur[t] = acc - v; }
    if (t == 0) bo[nbk] = e;
}

// ---------------- two-phase pair scatter (LDS counts, 1 global atomic per block-bucket) ----------------
__global__ __launch_bounds__(256) void k_pair2(const int* __restrict__ src, const int* __restrict__ dst,
                                               int* __restrict__ bcur, int2* __restrict__ pairs,
                                               int nbk, int e) {
    __shared__ int cnt[NBK_MAX];
    __shared__ int base[NBK_MAX];
    const int t = threadIdx.x;
    for (int b = t; b < nbk; b += 256) cnt[b] = 0;
    __syncthreads();
    const int e0 = blockIdx.x * EPB;
    int s[16], d[16], lo[16];
    #pragma unroll
    for (int j = 0; j < 16; ++j) {
        int idx = e0 + j * 256 + t;
        if (idx < e) {
            s[j] = src[idx];
            d[j] = dst[idx];
            lo[j] = atomicAdd(&cnt[d[j] >> BSH], 1);
        }
    }
    __syncthreads();
    for (int b = t; b < nbk; b += 256)
        base[b] = cnt[b] ? atomicAdd(&bcur[b], cnt[b]) : 0;
    __syncthreads();
    #pragma unroll
    for (int j = 0; j < 16; ++j) {
        int idx = e0 + j * 256 + t;
        if (idx < e) pairs[base[d[j] >> BSH] + lo[j]] = make_int2(s[j], d[j]);
    }
}

// ---------------- per-bucket degree (LDS histogram, plain stores) ----------------
__global__ __launch_bounds__(256) void k_bdeg(const int2* __restrict__ pairs, const int* __restrict__ bo,
                                              int* __restrict__ deg, int n) {
    __shared__ int cnt[128];
    const int b = blockIdx.x, t = threadIdx.x;
    if (t < 128) cnt[t] = 0;
    __syncthreads();
    int beg = bo[b], end = bo[b + 1];
    for (int i = beg + t; i < end; i += 256) atomicAdd(&cnt[pairs[i].y & 127], 1);
    __syncthreads();
    int node = (b << BSH) + t;
    if (t < 128 && node < n) deg[node] = cnt[t];
}

// ---------------- 3-kernel exclusive scan over deg ----------------
__global__ __launch_bounds__(256) void k_scan1(const int* __restrict__ deg, int* __restrict__ partial,
                                               int* __restrict__ bsum, int n) {
    __shared__ int sm[256];
    int t = threadIdx.x;
    int i = blockIdx.x * 256 + t;
    int v = (i < n) ? deg[i] : 0;
    sm[t] = v;
    __syncthreads();
    int acc = v;
    for (int off = 1; off < 256; off <<= 1) {
        int u = (t >= off) ? sm[t - off] : 0;
        __syncthreads();
        acc += u;
        sm[t] = acc;
        __syncthreads();
    }
    if (i < n) partial[i] = acc;
    if (t == 255) bsum[blockIdx.x] = acc;
}

__global__ __launch_bounds__(512) void k_scan2(const int* __restrict__ bsum, int* __restrict__ boff, int nb) {
    __shared__ int sm[512];
    int t = threadIdx.x;
    int v = (t < nb) ? bsum[t] : 0;
    sm[t] = v;
    __syncthreads();
    int acc = v;
    for (int off = 1; off < 512; off <<= 1) {
        int u = (t >= off) ? sm[t - off] : 0;
        __syncthreads();
        acc += u;
        sm[t] = acc;
        __syncthreads();
    }
    if (t < nb) boff[t] = acc - v;
}

__global__ __launch_bounds__(256) void k_scan3(const int* __restrict__ deg, const int* __restrict__ partial,
                                               const int* __restrict__ boff, int* __restrict__ rowptr,
                                               float* __restrict__ dinv, int n, int e) {
    int i = blockIdx.x * 256 + threadIdx.x;
    if (i >= n) return;
    rowptr[i] = boff[blockIdx.x] + partial[i] - deg[i];
    dinv[i] = rsqrtf((float)(deg[i] + 1));
    if (i == 0) rowptr[n] = e;
}

// ---------------- per-bucket CSR fill (LDS cursors seeded from rowptr) ----------------
__global__ __launch_bounds__(256) void k_bfill(const int2* __restrict__ pairs, const int* __restrict__ bo,
                                               const int* __restrict__ rowptr, int* __restrict__ csr_src,
                                               int n) {
    __shared__ int cur[128];
    const int b = blockIdx.x, t = threadIdx.x;
    int node = (b << BSH) + t;
    if (t < 128) cur[t] = (node < n) ? rowptr[node] : 0;
    __syncthreads();
    int beg = bo[b], end = bo[b + 1];
    for (int i = beg + t; i < end; i += 256) {
        int2 pr = pairs[i];
        int p = atomicAdd(&cur[pr.y & 127], 1);
        csr_src[p] = pr.x;
    }
}

// ---------------- W1 -> fp16 (once) ----------------
__global__ void k_whalf(const float* __restrict__ W1, _Float16* __restrict__ Wh, int total) {
    int i = blockIdx.x * 256 + threadIdx.x;
    if (i < total) Wh[i] = (_Float16)W1[i];
}

// ---------------- GEMM1: W-in-LDS (staged once), barrier-free K-loop, fp16 MFMA ----------------
// Block = 64 M-rows, 4 waves; wave owns 16 rows x all 128 N.
// All 16 x-loads issued up front (one HBM latency per wave); K-loop is pure ds_read+MFMA.
__global__ __launch_bounds__(256) void k_gemm(const float* __restrict__ x,
                                              const _Float16* __restrict__ Wh,
                                              const float* __restrict__ dinv,
                                              __half* __restrict__ hs, int n) {
    __shared__ _Float16 Ws[HID][WPAD];   // 67.6 KB
    const int tid = threadIdx.x;
    const int l   = tid & 63;
    const int w   = tid >> 6;
    const int fr  = l & 15;
    const int kg  = l >> 4;
    const int i0  = blockIdx.x * 64 + w * 16;

    const int r0 = i0 + fr;
    const float* xp = &x[(size_t)(r0 < n ? r0 : 0) * FIN + kg * 8];

    // issue the whole x row-slice up front (16 x dwordx4 in flight)
    float4 xv[8][2];
    #pragma unroll
    for (int ks = 0; ks < 8; ++ks) {
        xv[ks][0] = *(const float4*)&xp[ks * 32];
        xv[ks][1] = *(const float4*)&xp[ks * 32 + 4];
    }

    // cooperative W staging: 4096 chunks of 8 halfs, coalesced global reads
    #pragma unroll
    for (int j = 0; j < 16; ++j) {
        int c    = j * 256 + tid;
        int row  = c >> 5;
        int col8 = c & 31;
        *(half8v*)&Ws[row][col8 * 8] = *(const half8v*)&Wh[row * FIN + col8 * 8];
    }
    __syncthreads();

    f32x4 acc[8] = {};
    #pragma unroll
    for (int ks = 0; ks < 8; ++ks) {
        half8v ha;
        ha[0] = (_Float16)xv[ks][0].x; ha[1] = (_Float16)xv[ks][0].y;
        ha[2] = (_Float16)xv[ks][0].z; ha[3] = (_Float16)xv[ks][0].w;
        ha[4] = (_Float16)xv[ks][1].x; ha[5] = (_Float16)xv[ks][1].y;
        ha[6] = (_Float16)xv[ks][1].z; ha[7] = (_Float16)xv[ks][1].w;
        #pragma unroll
        for (int nt = 0; nt < 8; ++nt) {
            half8v hb = *(const half8v*)&Ws[nt * 16 + fr][kg * 8 + ks * 32];
            acc[nt] = __builtin_amdgcn_mfma_f32_16x16x32_f16(ha, hb, acc[nt], 0, 0, 0);
        }
    }

    // D(m,n): row = kg*4 + reg (M), col = fr (N)
    int rbase = i0 + kg * 4;
    if (rbase < n) {
        float4 dv = *(const float4*)&dinv[rbase];
        #pragma unroll
        for (int nt = 0; nt < 8; ++nt) {
            f32x4 c = acc[nt];
            int col = nt * 16 + fr;
            #pragma unroll
            for (int r = 0; r < 4; ++r) {
                int gi = rbase + r;
                if (gi < n)
                    hs[(size_t)gi * HID + col] = __float2half(((const float*)&c)[r] * ((const float*)&dv)[r]);
            }
        }
    }
}

// ---------------- layer-1 aggregation fused with layer-2 dot ----------------
// one wave per node; hs rows are fp16 (lane owns features 2*lane, 2*lane+1)
__global__ __launch_bounds__(256) void k_agg1(const unsigned int* __restrict__ hs,
                                              const int* __restrict__ rowptr,
                                              const int* __restrict__ csr_src,
                                              const float* __restrict__ dinv,
                                              const float* __restrict__ b1, const float* __restrict__ W2,
                                              float* __restrict__ zs, int n) {
    int i = (blockIdx.x << 2) + (threadIdx.x >> 6);
    if (i >= n) return;
    const int lane = threadIdx.x & 63;

    unsigned int sv = hs[(i << 6) + lane];                 // self-loop term
    float2 a = __half22float2(*reinterpret_cast<__half2*>(&sv));
    float ax = a.x, ay = a.y;

    int e = rowptr[i];
    const int end = rowptr[i + 1];
    while (e < end) {
        int cnt = end - e;
        if (cnt > 64) cnt = 64;
        int sidx = (lane < cnt) ? csr_src[e + lane] : 0;
        int j = 0;
        for (; j + 2 <= cnt; j += 2) {
            int s0 = __shfl(sidx, j, 64);
            int s1 = __shfl(sidx, j + 1, 64);
            unsigned int v0 = hs[(s0 << 6) + lane];
            unsigned int v1 = hs[(s1 << 6) + lane];
            float2 f0 = __half22float2(*reinterpret_cast<__half2*>(&v0));
            float2 f1 = __half22float2(*reinterpret_cast<__half2*>(&v1));
            ax += f0.x; ay += f0.y;
            ax += f1.x; ay += f1.y;
        }
        if (j < cnt) {
            int s0 = __shfl(sidx, j, 64);
            unsigned int v0 = hs[(s0 << 6) + lane];
            float2 f0 = __half22float2(*reinterpret_cast<__half2*>(&v0));
            ax += f0.x; ay += f0.y;
        }
        e += cnt;
    }
    float di = dinv[i];
    float2 bb = ((const float2*)b1)[lane];
    float h0 = fmaxf(ax * di + bb.x, 0.f);
    float h1 = fmaxf(ay * di + bb.y, 0.f);
    float2 w2 = ((const float2*)W2)[lane];
    float z = h0 * w2.x + h1 * w2.y;
    #pragma unroll
    for (int off = 32; off; off >>= 1) z += __shfl_xor(z, off, 64);
    if (lane == 0) zs[i] = z * di;
}

// ---------------- layer-2 aggregation ----------------
__global__ void k_agg2(const float* __restrict__ zs, const int* __restrict__ rowptr,
                       const int* __restrict__ csr_src, const float* __restrict__ dinv,
                       const float* __restrict__ b2, float* __restrict__ out, int n) {
    int i = blockIdx.x * blockDim.x + threadIdx.x;
    if (i >= n) return;
    float acc = zs[i];
    int beg = rowptr[i], end = rowptr[i + 1];
    for (int e = beg; e < end; ++e) acc += zs[csr_src[e]];
    out[i] = acc * dinv[i] + b2[0];
}

extern "C" void kernel_launch(void* const* d_in, const int* in_sizes, int n_in,
                              void* d_out, int out_size, void* d_ws, size_t ws_size,
                              hipStream_t stream) {
    const float* x  = (const float*)d_in[0];
    const int*   ei = (const int*)d_in[1];
    const float* W1 = (const float*)d_in[2];
    const float* b1 = (const float*)d_in[3];
    const float* W2 = (const float*)d_in[4];
    const float* b2 = (const float*)d_in[5];
    float* out = (float*)d_out;

    const int n = in_sizes[0] / FIN;
    const int e = in_sizes[1] / 2;
    const int* src = ei;
    const int* dst = ei + e;
    const int nbk = (n + (1 << BSH) - 1) >> BSH;

    char* p = (char*)d_ws;
    auto carve = [&](size_t bytes) { char* q = p; p += (bytes + 255) & ~(size_t)255; return q; };
    int*            deg     = (int*)carve((size_t)n * 4);
    int*            bcnt    = (int*)carve((size_t)NBK_MAX * 4);
    int*            partial = (int*)carve((size_t)n * 4);
    int*            bsum    = (int*)carve(4096);
    int*            boff    = (int*)carve(4096);
    int*            bo      = (int*)carve((size_t)(NBK_MAX + 1) * 4);
    int*            bcur    = (int*)carve((size_t)NBK_MAX * 4);
    int*            rowptr  = (int*)carve((size_t)(n + 1) * 4);
    float*          dinv    = (float*)carve((size_t)n * 4);
    int*            csr     = (int*)carve((size_t)e * 4);
    int2*           pairs   = (int2*)carve((size_t)e * 8);
    __half*         hs      = (__half*)carve((size_t)n * HID * 2);
    float*          zs      = (float*)carve((size_t)n * 4);
    _Float16*       Wh      = (_Float16*)carve((size_t)HID * FIN * 2);

    hipMemsetAsync(bcnt, 0, (size_t)NBK_MAX * 4, stream);

    const int nb  = (n + 255) / 256;
    const int neb = (e + EPB - 1) / EPB;
    k_whalf<<<(HID * FIN + 255) / 256, 256, 0, stream>>>(W1, Wh, HID * FIN);
    k_hist <<<neb, 256, 0, stream>>>(dst, bcnt, nbk, e);
    k_bscan<<<1, 1024, 0, stream>>>(bcnt, bo, bcur, nbk, e);
    k_pair2<<<neb, 256, 0, stream>>>(src, dst, bcur, pairs, nbk, e);
    k_bdeg <<<nbk, 256, 0, stream>>>(pairs, bo, deg, n);
    k_scan1<<<nb, 256, 0, stream>>>(deg, partial, bsum, n);
    k_scan2<<<1, 512, 0, stream>>>(bsum, boff, nb);
    k_scan3<<<nb, 256, 0, stream>>>(deg, partial, boff, rowptr, dinv, n, e);
    k_bfill<<<nbk, 256, 0, stream>>>(pairs, bo, rowptr, csr, n);
    k_gemm <<<(n + 63) / 64, 256, 0, stream>>>(x, Wh, dinv, hs, n);
    k_agg1 <<<(n + 3) / 4, 256, 0, stream>>>((const unsigned int*)hs, rowptr, csr, dinv, b1, W2, zs, n);
    k_agg2 <<<(n + 255) / 256, 256, 0, stream>>>(zs, rowptr, csr, dinv, b2, out, n);
}

// Round 8
// 187.869 us; speedup vs baseline: 1.3091x; 1.0026x over previous
//
#include <hip/hip_runtime.h>
#include <hip/hip_bf16.h>
#include <hip/hip_fp16.h>

#define FIN 256
#define HID 128
#define BSH 7            // bucket = dst >> 7 (128 nodes/bucket)
#define NBK_MAX 1024
#define EPB 4096         // edges per block in hist/pair kernels
#define WPAD 264         // 256 + 8 halfs row pad

typedef __attribute__((ext_vector_type(8))) _Float16 half8v;  // f16x8 MFMA frag (4 VGPRs)
typedef __attribute__((ext_vector_type(4))) float f32x4;      // MFMA acc

// ---------------- bucket histogram via LDS ----------------
__global__ __launch_bounds__(256) void k_hist(const int* __restrict__ dst, int* __restrict__ bcnt,
                                              int nbk, int e) {
    __shared__ int cnt[NBK_MAX];
    int t = threadIdx.x;
    for (int b = t; b < nbk; b += 256) cnt[b] = 0;
    __syncthreads();
    int e0 = blockIdx.x * EPB;
    #pragma unroll
    for (int j = 0; j < EPB; j += 256) {
        int idx = e0 + j + t;
        if (idx < e) atomicAdd(&cnt[dst[idx] >> BSH], 1);
    }
    __syncthreads();
    for (int b = t; b < nbk; b += 256)
        if (cnt[b]) atomicAdd(&bcnt[b], cnt[b]);
}

// ---------------- bucket scan (single block) ----------------
__global__ __launch_bounds__(1024) void k_bscan(const int* __restrict__ bcnt, int* __restrict__ bo,
                                                int* __restrict__ bcur, int nbk, int e) {
    __shared__ int sm[1024];
    int t = threadIdx.x;
    int v = (t < nbk) ? bcnt[t] : 0;
    sm[t] = v;
    __syncthreads();
    int acc = v;
    for (int off = 1; off < 1024; off <<= 1) {
        int u = (t >= off) ? sm[t - off] : 0;
        __syncthreads();
        acc += u;
        sm[t] = acc;
        __syncthreads();
    }
    if (t < nbk) { bo[t] = acc - v; bcur[t] = acc - v; }
    if (t == 0) bo[nbk] = e;
}

// ---------------- two-phase pair scatter (LDS counts, 1 global atomic per block-bucket) ----------------
__global__ __launch_bounds__(256) void k_pair2(const int* __restrict__ src, const int* __restrict__ dst,
                                               int* __restrict__ bcur, int2* __restrict__ pairs,
                                               int nbk, int e) {
    __shared__ int cnt[NBK_MAX];
    __shared__ int base[NBK_MAX];
    const int t = threadIdx.x;
    for (int b = t; b < nbk; b += 256) cnt[b] = 0;
    __syncthreads();
    const int e0 = blockIdx.x * EPB;
    int s[16], d[16], lo[16];
    #pragma unroll
    for (int j = 0; j < 16; ++j) {
        int idx = e0 + j * 256 + t;
        if (idx < e) {
            s[j] = src[idx];
            d[j] = dst[idx];
            lo[j] = atomicAdd(&cnt[d[j] >> BSH], 1);
        }
    }
    __syncthreads();
    for (int b = t; b < nbk; b += 256)
        base[b] = cnt[b] ? atomicAdd(&bcur[b], cnt[b]) : 0;
    __syncthreads();
    #pragma unroll
    for (int j = 0; j < 16; ++j) {
        int idx = e0 + j * 256 + t;
        if (idx < e) pairs[base[d[j] >> BSH] + lo[j]] = make_int2(s[j], d[j]);
    }
}

// ---------------- per-bucket degree (LDS histogram, plain stores) ----------------
__global__ __launch_bounds__(256) void k_bdeg(const int2* __restrict__ pairs, const int* __restrict__ bo,
                                              int* __restrict__ deg, int n) {
    __shared__ int cnt[128];
    const int b = blockIdx.x, t = threadIdx.x;
    if (t < 128) cnt[t] = 0;
    __syncthreads();
    int beg = bo[b], end = bo[b + 1];
    for (int i = beg + t; i < end; i += 256) atomicAdd(&cnt[pairs[i].y & 127], 1);
    __syncthreads();
    int node = (b << BSH) + t;
    if (t < 128 && node < n) deg[node] = cnt[t];
}

// ---------------- 3-kernel exclusive scan over deg ----------------
__global__ __launch_bounds__(256) void k_scan1(const int* __restrict__ deg, int* __restrict__ partial,
                                               int* __restrict__ bsum, int n) {
    __shared__ int sm[256];
    int t = threadIdx.x;
    int i = blockIdx.x * 256 + t;
    int v = (i < n) ? deg[i] : 0;
    sm[t] = v;
    __syncthreads();
    int acc = v;
    for (int off = 1; off < 256; off <<= 1) {
        int u = (t >= off) ? sm[t - off] : 0;
        __syncthreads();
        acc += u;
        sm[t] = acc;
        __syncthreads();
    }
    if (i < n) partial[i] = acc;
    if (t == 255) bsum[blockIdx.x] = acc;
}

__global__ __launch_bounds__(512) void k_scan2(const int* __restrict__ bsum, int* __restrict__ boff, int nb) {
    __shared__ int sm[512];
    int t = threadIdx.x;
    int v = (t < nb) ? bsum[t] : 0;
    sm[t] = v;
    __syncthreads();
    int acc = v;
    for (int off = 1; off < 512; off <<= 1) {
        int u = (t >= off) ? sm[t - off] : 0;
        __syncthreads();
        acc += u;
        sm[t] = acc;
        __syncthreads();
    }
    if (t < nb) boff[t] = acc - v;
}

__global__ __launch_bounds__(256) void k_scan3(const int* __restrict__ deg, const int* __restrict__ partial,
                                               const int* __restrict__ boff, int* __restrict__ rowptr,
                                               float* __restrict__ dinv, int n, int e) {
    int i = blockIdx.x * 256 + threadIdx.x;
    if (i >= n) return;
    rowptr[i] = boff[blockIdx.x] + partial[i] - deg[i];
    dinv[i] = rsqrtf((float)(deg[i] + 1));
    if (i == 0) rowptr[n] = e;
}

// ---------------- per-bucket CSR fill (LDS cursors seeded from rowptr) ----------------
__global__ __launch_bounds__(256) void k_bfill(const int2* __restrict__ pairs, const int* __restrict__ bo,
                                               const int* __restrict__ rowptr, int* __restrict__ csr_src,
                                               int n) {
    __shared__ int cur[128];
    const int b = blockIdx.x, t = threadIdx.x;
    int node = (b << BSH) + t;
    if (t < 128) cur[t] = (node < n) ? rowptr[node] : 0;
    __syncthreads();
    int beg = bo[b], end = bo[b + 1];
    for (int i = beg + t; i < end; i += 256) {
        int2 pr = pairs[i];
        int p = atomicAdd(&cur[pr.y & 127], 1);
        csr_src[p] = pr.x;
    }
}

// ---------------- W1 -> fp16 (once) ----------------
__global__ void k_whalf(const float* __restrict__ W1, _Float16* __restrict__ Wh, int total) {
    int i = blockIdx.x * 256 + threadIdx.x;
    if (i < total) Wh[i] = (_Float16)W1[i];
}

// ---------------- GEMM1: W-in-LDS (staged once), barrier-free K-loop, fp16 MFMA ----------------
// Block = 64 M-rows, 4 waves; wave owns 16 rows x all 128 N.
// All 16 x-loads issued up front (one HBM latency per wave); K-loop is pure ds_read+MFMA.
__global__ __launch_bounds__(256) void k_gemm(const float* __restrict__ x,
                                              const _Float16* __restrict__ Wh,
                                              const float* __restrict__ dinv,
                                              __half* __restrict__ hs, int n) {
    __shared__ _Float16 Ws[HID][WPAD];   // 67.6 KB
    const int tid = threadIdx.x;
    const int l   = tid & 63;
    const int w   = tid >> 6;
    const int fr  = l & 15;
    const int kg  = l >> 4;
    const int i0  = blockIdx.x * 64 + w * 16;

    const int r0 = i0 + fr;
    const float* xp = &x[(size_t)(r0 < n ? r0 : 0) * FIN + kg * 8];

    // issue the whole x row-slice up front (16 x dwordx4 in flight)
    float4 xv[8][2];
    #pragma unroll
    for (int ks = 0; ks < 8; ++ks) {
        xv[ks][0] = *(const float4*)&xp[ks * 32];
        xv[ks][1] = *(const float4*)&xp[ks * 32 + 4];
    }

    // cooperative W staging: 4096 chunks of 8 halfs, coalesced global reads
    #pragma unroll
    for (int j = 0; j < 16; ++j) {
        int c    = j * 256 + tid;
        int row  = c >> 5;
        int col8 = c & 31;
        *(half8v*)&Ws[row][col8 * 8] = *(const half8v*)&Wh[row * FIN + col8 * 8];
    }
    __syncthreads();

    f32x4 acc[8] = {};
    #pragma unroll
    for (int ks = 0; ks < 8; ++ks) {
        half8v ha;
        ha[0] = (_Float16)xv[ks][0].x; ha[1] = (_Float16)xv[ks][0].y;
        ha[2] = (_Float16)xv[ks][0].z; ha[3] = (_Float16)xv[ks][0].w;
        ha[4] = (_Float16)xv[ks][1].x; ha[5] = (_Float16)xv[ks][1].y;
        ha[6] = (_Float16)xv[ks][1].z; ha[7] = (_Float16)xv[ks][1].w;
        #pragma unroll
        for (int nt = 0; nt < 8; ++nt) {
            half8v hb = *(const half8v*)&Ws[nt * 16 + fr][kg * 8 + ks * 32];
            acc[nt] = __builtin_amdgcn_mfma_f32_16x16x32_f16(ha, hb, acc[nt], 0, 0, 0);
        }
    }

    // D(m,n): row = kg*4 + reg (M), col = fr (N)
    int rbase = i0 + kg * 4;
    if (rbase < n) {
        float4 dv = *(const float4*)&dinv[rbase];
        #pragma unroll
        for (int nt = 0; nt < 8; ++nt) {
            f32x4 c = acc[nt];
            int col = nt * 16 + fr;
            #pragma unroll
            for (int r = 0; r < 4; ++r) {
                int gi = rbase + r;
                if (gi < n)
                    hs[(size_t)gi * HID + col] = __float2half(((const float*)&c)[r] * ((const float*)&dv)[r]);
            }
        }
    }
}

// ---------------- layer-1 aggregation fused with layer-2 dot ----------------
// one wave per node; hs rows are fp16 (lane owns features 2*lane, 2*lane+1)
__global__ __launch_bounds__(256) void k_agg1(const unsigned int* __restrict__ hs,
                                              const int* __restrict__ rowptr,
                                              const int* __restrict__ csr_src,
                                              const float* __restrict__ dinv,
                                              const float* __restrict__ b1, const float* __restrict__ W2,
                                              float* __restrict__ zs, int n) {
    int i = (blockIdx.x << 2) + (threadIdx.x >> 6);
    if (i >= n) return;
    const int lane = threadIdx.x & 63;

    unsigned int sv = hs[(i << 6) + lane];                 // self-loop term
    float2 a = __half22float2(*reinterpret_cast<__half2*>(&sv));
    float ax = a.x, ay = a.y;

    int e = rowptr[i];
    const int end = rowptr[i + 1];
    while (e < end) {
        int cnt = end - e;
        if (cnt > 64) cnt = 64;
        int sidx = (lane < cnt) ? csr_src[e + lane] : 0;
        int j = 0;
        for (; j + 2 <= cnt; j += 2) {
            int s0 = __shfl(sidx, j, 64);
            int s1 = __shfl(sidx, j + 1, 64);
            unsigned int v0 = hs[(s0 << 6) + lane];
            unsigned int v1 = hs[(s1 << 6) + lane];
            float2 f0 = __half22float2(*reinterpret_cast<__half2*>(&v0));
            float2 f1 = __half22float2(*reinterpret_cast<__half2*>(&v1));
            ax += f0.x; ay += f0.y;
            ax += f1.x; ay += f1.y;
        }
        if (j < cnt) {
            int s0 = __shfl(sidx, j, 64);
            unsigned int v0 = hs[(s0 << 6) + lane];
            float2 f0 = __half22float2(*reinterpret_cast<__half2*>(&v0));
            ax += f0.x; ay += f0.y;
        }
        e += cnt;
    }
    float di = dinv[i];
    float2 bb = ((const float2*)b1)[lane];
    float h0 = fmaxf(ax * di + bb.x, 0.f);
    float h1 = fmaxf(ay * di + bb.y, 0.f);
    float2 w2 = ((const float2*)W2)[lane];
    float z = h0 * w2.x + h1 * w2.y;
    #pragma unroll
    for (int off = 32; off; off >>= 1) z += __shfl_xor(z, off, 64);
    if (lane == 0) zs[i] = z * di;
}

// ---------------- layer-2 aggregation ----------------
__global__ void k_agg2(const float* __restrict__ zs, const int* __restrict__ rowptr,
                       const int* __restrict__ csr_src, const float* __restrict__ dinv,
                       const float* __restrict__ b2, float* __restrict__ out, int n) {
    int i = blockIdx.x * blockDim.x + threadIdx.x;
    if (i >= n) return;
    float acc = zs[i];
    int beg = rowptr[i], end = rowptr[i + 1];
    for (int e = beg; e < end; ++e) acc += zs[csr_src[e]];
    out[i] = acc * dinv[i] + b2[0];
}

extern "C" void kernel_launch(void* const* d_in, const int* in_sizes, int n_in,
                              void* d_out, int out_size, void* d_ws, size_t ws_size,
                              hipStream_t stream) {
    const float* x  = (const float*)d_in[0];
    const int*   ei = (const int*)d_in[1];
    const float* W1 = (const float*)d_in[2];
    const float* b1 = (const float*)d_in[3];
    const float* W2 = (const float*)d_in[4];
    const float* b2 = (const float*)d_in[5];
    float* out = (float*)d_out;

    const int n = in_sizes[0] / FIN;
    const int e = in_sizes[1] / 2;
    const int* src = ei;
    const int* dst = ei + e;
    const int nbk = (n + (1 << BSH) - 1) >> BSH;

    char* p = (char*)d_ws;
    auto carve = [&](size_t bytes) { char* q = p; p += (bytes + 255) & ~(size_t)255; return q; };
    int*            deg     = (int*)carve((size_t)n * 4);
    int*            bcnt    = (int*)carve((size_t)NBK_MAX * 4);
    int*            partial = (int*)carve((size_t)n * 4);
    int*            bsum    = (int*)carve(4096);
    int*            boff    = (int*)carve(4096);
    int*            bo      = (int*)carve((size_t)(NBK_MAX + 1) * 4);
    int*            bcur    = (int*)carve((size_t)NBK_MAX * 4);
    int*            rowptr  = (int*)carve((size_t)(n + 1) * 4);
    float*          dinv    = (float*)carve((size_t)n * 4);
    int*            csr     = (int*)carve((size_t)e * 4);
    int2*           pairs   = (int2*)carve((size_t)e * 8);
    __half*         hs      = (__half*)carve((size_t)n * HID * 2);
    float*          zs      = (float*)carve((size_t)n * 4);
    _Float16*       Wh      = (_Float16*)carve((size_t)HID * FIN * 2);

    hipMemsetAsync(bcnt, 0, (size_t)NBK_MAX * 4, stream);

    const int nb  = (n + 255) / 256;
    const int neb = (e + EPB - 1) / EPB;
    k_whalf<<<(HID * FIN + 255) / 256, 256, 0, stream>>>(W1, Wh, HID * FIN);
    k_hist <<<neb, 256, 0, stream>>>(dst, bcnt, nbk, e);
    k_bscan<<<1, 1024, 0, stream>>>(bcnt, bo, bcur, nbk, e);
    k_pair2<<<neb, 256, 0, stream>>>(src, dst, bcur, pairs, nbk, e);
    k_bdeg <<<nbk, 256, 0, stream>>>(pairs, bo, deg, n);
    k_scan1<<<nb, 256, 0, stream>>>(deg, partial, bsum, n);
    k_scan2<<<1, 512, 0, stream>>>(bsum, boff, nb);
    k_scan3<<<nb, 256, 0, stream>>>(deg, partial, boff, rowptr, dinv, n, e);
    k_bfill<<<nbk, 256, 0, stream>>>(pairs, bo, rowptr, csr, n);
    k_gemm <<<(n + 63) / 64, 256, 0, stream>>>(x, Wh, dinv, hs, n);
    k_agg1 <<<(n + 3) / 4, 256, 0, stream>>>((const unsigned int*)hs, rowptr, csr, dinv, b1, W2, zs, n);
    k_agg2 <<<(n + 255) / 256, 256, 0, stream>>>(zs, rowptr, csr, dinv, b2, out, n);
}